// Round 15
// baseline (492.547 us; speedup 1.0000x reference)
//
#include <hip/hip_runtime.h>

// VQ argmin: exact bit-level emulation of numpy fp32 reference:
//   A  = np.sum(flat*flat, axis=1)     (numpy pairwise-sum tree, fp32)
//   M2 = (2*flat) @ emb.T              (BLAS: sequential fp32 fma chain over d)
//   dist = (A - M2) + ee;  argmin_k (first-min ties)
// z_e_x: [B=16, D=256, H=64, W=64] fp32; embedding: [K=1024, D=256] fp32
// out: int32 [65536]
//
// R17: R16 (session best 465us; vq 403, VALU 70%) minus the residual spill.
// R16's WRITE_SIZE=43MB + Occupancy 33.6% (<50% grid cap) = bkey/bk[32]
// VGPRs (touched only 4x/kernel) overflow the 128 budget and scratch
// throttles residency. Changes:
//  1. running best moved to LDS (best[wave][n], 512B/block): per-supertile
//     fold -> 6-step shfl u64 butterfly -> lane0 u64-min merge. Frees ~32
//     VGPRs -> demand ~90 << 128, no spill.
//  2. An loaded at fold time (4x, scalar, L1-hot) instead of hoisted ->
//     frees 16 SGPRs for z s_load scheduling.
//  3. else identical to R16: KL=4, NW=16, er 2-row ping-pong (16 VGPR),
//     z consumed directly (R14-proven s_load scalarization), (256,4),
//     grid 1024, fused prep kernel.
// Exact ties: u64 (order-encoded distbits, k) min at every level -- within
// lane (q ascending, strict <), across lanes (butterfly min, lowest k on
// tie), across supertiles (LDS min; supertiles ascend in k). Same
// first-min semantics verified absmax=0 in R13-R16.

#define D_DIM  256
#define K_DIM  1024
#define HW     4096
#define N_TOT  65536
#define NW     16                 // n's per wave
#define KL     4                  // k's per lane
#define F32MAX 3.402823466e38f

// ---- fused prep: [0,256) et transpose | [256,768) A | [768,772) ee

__global__ void prep_kernel(const float* __restrict__ z, const float* __restrict__ e,
                            float* __restrict__ eT, float* __restrict__ A,
                            float* __restrict__ ee) {
#pragma clang fp contract(off)
    const int bid = blockIdx.x;
    const int t   = threadIdx.x;

    if (bid < 256) {
        // ---- transpose + fold the exact x2: eT[d][k] = 2*emb[k][d]
        __shared__ float tl[32][33];
        const int k0 = (bid & 31) * 32;
        const int d0 = (bid >> 5) * 32;
        const int tx = t & 31;
        const int ty = t >> 5;          // 0..7
        #pragma unroll
        for (int i = 0; i < 32; i += 8)
            tl[ty + i][tx] = 2.0f * e[(size_t)(k0 + ty + i) * D_DIM + d0 + tx];
        __syncthreads();
        #pragma unroll
        for (int i = 0; i < 32; i += 8)
            eT[(size_t)(d0 + ty + i) * K_DIM + k0 + tx] = tl[tx][ty + i];
    } else if (bid < 768) {
        // ---- A = numpy pairwise ||z_n||^2: 2 threads/n, one 128-half each
        // (independent 8-acc chains; total = s0 + s1). Bitwise-exact.
        const int tt = (bid - 256) * 256 + t;    // 0 .. 2*N_TOT-1
        const int n  = tt >> 1;
        const int h  = tt & 1;
        const int b  = n >> 12;
        const int hw = n & (HW - 1);
        const float* base = z + (size_t)b * D_DIM * HW + hw + (size_t)(h * 128) * HW;
        float r[8];
        #pragma unroll
        for (int j = 0; j < 8; ++j) { float v = base[(size_t)j * HW]; r[j] = v * v; }
        #pragma unroll
        for (int i = 8; i < 128; i += 8) {
            #pragma unroll
            for (int j = 0; j < 8; ++j) {
                float v = base[(size_t)(i + j) * HW];
                r[j] = r[j] + v * v;
            }
        }
        float s = ((r[0] + r[1]) + (r[2] + r[3])) + ((r[4] + r[5]) + (r[6] + r[7]));
        float other = __shfl_xor(s, 1);
        if (h == 0) A[n] = s + other;
    } else {
        // ---- ee = numpy pairwise ||e_k||^2 (two 128-halves of 8 accs)
        const int k = (bid - 768) * 256 + t;
        const float* row = e + (size_t)k * D_DIM;
        float total = 0.0f;
        #pragma unroll
        for (int h = 0; h < 2; ++h) {
            const float* a = row + h * 128;
            float r[8];
            #pragma unroll
            for (int j = 0; j < 8; ++j) { float v = a[j]; r[j] = v * v; }
            #pragma unroll
            for (int i = 8; i < 128; i += 8) {
                #pragma unroll
                for (int j = 0; j < 8; ++j) { float v = a[i + j]; r[j] = r[j] + v * v; }
            }
            float s = ((r[0] + r[1]) + (r[2] + r[3])) + ((r[4] + r[5]) + (r[6] + r[7]));
            total = (h == 0) ? s : (total + s);
        }
        ee[k] = total;
    }
}

// ---- main: wave owns 16 consecutive n (one b; z row = 64B contiguous,
// wave-uniform address -> compiler s_load_dwordx16) x 256 k per supertile
// (4 per lane, stride 64). er: 2-row VGPR ping-pong of 4 coalesced loads
// per row. Per 4-row iter: 16 er loads + 4 z s_loads + 256 v_fmac.

__launch_bounds__(256, 4)
__global__ void vq_kernel(const float* __restrict__ z, const float* __restrict__ eT,
                          const float* __restrict__ A, const float* __restrict__ ee,
                          int* __restrict__ out) {
#pragma clang fp contract(off)
    __shared__ unsigned long long best[4][NW];   // per-wave running best

    const int lane = threadIdx.x & 63;
    const int wid  = __builtin_amdgcn_readfirstlane(threadIdx.x >> 6);
    const int gw   = blockIdx.x * 4 + wid;       // 0..1023, wave-uniform
    const int n0   = gw * NW;
    const int b    = n0 >> 12;                   // NW | 4096: never spans b
    const int hw0  = n0 & (HW - 1);
    const float* __restrict__ zrow = z + (size_t)b * D_DIM * HW + hw0;

    if (lane < NW) best[wid][lane] = ~0ull;      // same-wave: no barrier

    #pragma unroll 1
    for (int kt = 0; kt < K_DIM / (64 * KL); ++kt) {   // 4 supertiles
        const int kb = kt * 64 * KL;
        const float* __restrict__ ep = eT + kb + lane;   // per-lane k base

        float acc[NW][KL];
        #pragma unroll
        for (int i = 0; i < NW; ++i)
            #pragma unroll
            for (int q = 0; q < KL; ++q) acc[i][q] = 0.0f;

        // er ping-pong buffers only (16 VGPR); z is consumed directly
        // (R14-proven scalarization; NO arrays -> no spill).
        float ea[2][KL], eb[2][KL];
        #pragma unroll
        for (int r = 0; r < 2; ++r)
            #pragma unroll
            for (int q = 0; q < KL; ++q)
                ea[r][q] = ep[(size_t)r * K_DIM + q * 64];

        #pragma unroll 1
        for (int d = 0; d < D_DIM; d += 4) {
            // phase A: prefetch er rows d+2,d+3; compute rows d,d+1
            #pragma unroll
            for (int r = 0; r < 2; ++r)
                #pragma unroll
                for (int q = 0; q < KL; ++q)
                    eb[r][q] = ep[(size_t)(d + 2 + r) * K_DIM + q * 64];
            #pragma unroll
            for (int r = 0; r < 2; ++r) {
                const float* __restrict__ zr = zrow + (size_t)(d + r) * HW;
                #pragma unroll
                for (int i = 0; i < NW; ++i) {
                    const float zv = zr[i];          // uniform -> s_load
                    #pragma unroll
                    for (int q = 0; q < KL; ++q)
                        acc[i][q] = fmaf(zv, ea[r][q], acc[i][q]);
                }
            }
            // phase B: prefetch er rows d+4,d+5 (mask-wrap: tail values
            // dead, re-primed next supertile); compute rows d+2,d+3
            #pragma unroll
            for (int r = 0; r < 2; ++r) {
                const int dn = (d + 4 + r) & (D_DIM - 1);
                #pragma unroll
                for (int q = 0; q < KL; ++q)
                    ea[r][q] = ep[(size_t)dn * K_DIM + q * 64];
            }
            #pragma unroll
            for (int r = 0; r < 2; ++r) {
                const float* __restrict__ zr = zrow + (size_t)(d + 2 + r) * HW;
                #pragma unroll
                for (int i = 0; i < NW; ++i) {
                    const float zv = zr[i];          // uniform -> s_load
                    #pragma unroll
                    for (int q = 0; q < KL; ++q)
                        acc[i][q] = fmaf(zv, eb[r][q], acc[i][q]);
                }
            }
        }

        // fold supertile -> per-lane key -> butterfly -> LDS merge.
        // An loaded here (uniform, L1-hot after 1st supertile): not hoisted,
        // keeps SGPR/VGPR pressure off the hot loop.
        #pragma unroll
        for (int i = 0; i < NW; ++i) {
            const float An = A[n0 + i];
            unsigned int bkey = 0xFFFFFFFFu, bkk = 0u;
            #pragma unroll
            for (int q = 0; q < KL; ++q) {           // q ascending = k ascending
                const int kq = kb + q * 64 + lane;
                const float dist = (An - acc[i][q]) + ee[kq];
                unsigned int d32 = __float_as_uint(dist);
                d32 ^= (unsigned int)((int)d32 >> 31) | 0x80000000u;  // total order
                if (d32 < bkey) { bkey = d32; bkk = (unsigned int)kq; }
            }
            unsigned long long key =
                ((unsigned long long)bkey << 32) | (unsigned long long)bkk;
            #pragma unroll
            for (int m = 1; m < 64; m <<= 1) {       // 64-lane min, ties->low k
                unsigned long long o = __shfl_xor(key, m, 64);
                if (o < key) key = o;
            }
            if (lane == 0) {
                unsigned long long cur = best[wid][i];
                best[wid][i] = (key < cur) ? key : cur;
            }
        }
    }

    // one wave per n -> plain coalesced store by lanes 0..15
    if (lane < NW) out[n0 + lane] = (int)(best[wid][lane] & 0xFFFFFFFFull);
}

extern "C" void kernel_launch(void* const* d_in, const int* in_sizes, int n_in,
                              void* d_out, int out_size, void* d_ws, size_t ws_size,
                              hipStream_t stream) {
    const float* z   = (const float*)d_in[0];   // [16,256,64,64]
    const float* emb = (const float*)d_in[1];   // [1024,256]
    int* out = (int*)d_out;                     // [65536] int32

    float* wsEE = (float*)d_ws;                 // 1024
    float* wsA  = wsEE + K_DIM;                 // 65536
    float* wsET = wsA + N_TOT;                  // 262144

    prep_kernel<<<772, 256, 0, stream>>>(z, emb, wsET, wsA, wsEE);
    vq_kernel<<<N_TOT / NW / 4, 256, 0, stream>>>(z, wsET, wsA, wsEE, out);
}